// Round 4
// baseline (250.978 us; speedup 1.0000x reference)
//
#include <hip/hip_runtime.h>

#define SCALE 0.0625f  // C^-0.5 = 1/16

typedef __attribute__((ext_vector_type(4))) float f32x4;
typedef __attribute__((ext_vector_type(8))) short s16x8;

__device__ __forceinline__ unsigned short f2bf(float x) {
    unsigned u = __float_as_uint(x);
    u = u + 0x7FFF + ((u >> 16) & 1);   // RNE; inputs finite
    return (unsigned short)(u >> 16);
}

// ---------------------------------------------------------------------------
// prep1: blocks 0..15  -> q[b,c] = TO[b] . Wq[c] + bq[c]
//        blocks 16..31 -> WvB = bf16(Wv)   (row-major [co][o])
// ---------------------------------------------------------------------------
__global__ __launch_bounds__(256) void prep1_kernel(
    const float* __restrict__ TO,    // [2,1024]
    const float* __restrict__ Wq,    // [256,1024]
    const float* __restrict__ bq,    // [256]
    const float* __restrict__ Wv,    // [256,256]
    float* __restrict__ qbuf,        // [2,256]
    unsigned short* __restrict__ WvB)// [256,256] bf16
{
    const int blk = blockIdx.x;
    const int t   = threadIdx.x;
    if (blk < 16) {
        const int b    = blk >> 3;
        const int rblk = blk & 7;
        const int wv = t >> 6, l = t & 63;
        const float4* Wq4 = (const float4*)Wq;
        const float4* TO4 = (const float4*)TO;
        for (int rr = 0; rr < 8; ++rr) {
            const int c = rblk * 32 + wv * 8 + rr;
            float acc = 0.f;
#pragma unroll
            for (int i = 0; i < 4; ++i) {
                float4 wq = Wq4[c * 256 + i * 64 + l];
                float4 tv = TO4[b * 256 + i * 64 + l];
                acc = fmaf(wq.x, tv.x, acc);
                acc = fmaf(wq.y, tv.y, acc);
                acc = fmaf(wq.z, tv.z, acc);
                acc = fmaf(wq.w, tv.w, acc);
            }
#pragma unroll
            for (int mask = 1; mask < 64; mask <<= 1)
                acc += __shfl_xor(acc, mask, 64);
            if (l == 0) qbuf[b * 256 + c] = acc + bq[c];
        }
    } else {
        const int idx = blk - 16;   // 0..15, 4096 elements each
#pragma unroll
        for (int i = 0; i < 4; ++i) {
            const int e = idx * 4096 + i * 1024 + t * 4;
            const float4 f = ((const float4*)Wv)[e >> 2];
            ushort4 o;
            o.x = f2bf(f.x); o.y = f2bf(f.y);
            o.z = f2bf(f.z); o.w = f2bf(f.w);
            *(ushort4*)(WvB + e) = o;
        }
    }
}

// ---------------------------------------------------------------------------
// prep2: 16 blocks: qks[b,cp] = SCALE * sum_c q[c] Wk[c][cp]
// (q.bk term dropped: softmax-invariant)
// ---------------------------------------------------------------------------
__global__ __launch_bounds__(256) void prep2_kernel(
    const float* __restrict__ qbuf,  // [2,256]
    const float* __restrict__ Wk,    // [256,256]
    float* __restrict__ qks)         // [2,256] (pre-scaled)
{
    const int blk = blockIdx.x;
    const int t   = threadIdx.x;
    const int b = blk >> 3, j = blk & 7;
    const int col = t & 31, chunk = t >> 5;
    const int cp = j * 32 + col;
    float partial = 0.f;
#pragma unroll 8
    for (int cc = 0; cc < 32; ++cc) {
        const int c = chunk * 32 + cc;
        partial = fmaf(qbuf[b * 256 + c], Wk[c * 256 + cp], partial);
    }
    __shared__ float r2[8][32];
    r2[chunk][col] = partial;
    __syncthreads();
    if (t < 32) {
        float s = 0.f;
#pragma unroll
        for (int k = 0; k < 8; ++k) s += r2[k][t];
        qks[b * 256 + j * 32 + t] = SCALE * s;
    }
}

// ---------------------------------------------------------------------------
// pass 1: scores[b,m,px] = sum_c qks[b,c] * X[b,m,c,px]
//   512 blocks x 256 thr; thread = one pixel. Lanes = contiguous pixels ->
//   every load is a fully coalesced 256B row segment; qks[c] is a scalar
//   (uniform) load. NO cross-lane reduction, NO barriers, 16 loads in
//   flight per lane (unroll 4 x 4 accumulators). Pure 132 MB stream.
// ---------------------------------------------------------------------------
__global__ __launch_bounds__(256) void scores_kernel(
    const float* __restrict__ X,      // [2,16,256,4096]
    const float* __restrict__ qks,    // [2,256]
    float* __restrict__ scores)       // [2,16,4096]
{
    const int blk = blockIdx.x;              // 0..511
    const int bm  = blk >> 4;                // 0..31  (b*16+m)
    const int px  = ((blk & 15) << 8) + threadIdx.x;
    const float* __restrict__ Xr = X + bm * 1048576 + px;
    const float* __restrict__ qr = qks + (bm >> 4) * 256;
    float s0 = 0.f, s1 = 0.f, s2 = 0.f, s3 = 0.f;
#pragma unroll 4
    for (int c = 0; c < 256; c += 4) {
        s0 = fmaf(qr[c + 0], Xr[(c + 0) * 4096], s0);
        s1 = fmaf(qr[c + 1], Xr[(c + 1) * 4096], s1);
        s2 = fmaf(qr[c + 2], Xr[(c + 2) * 4096], s2);
        s3 = fmaf(qr[c + 3], Xr[(c + 3) * 4096], s3);
    }
    scores[bm * 4096 + px] = (s0 + s1) + (s2 + s3);
}

// ---------------------------------------------------------------------------
// pass 2: per 16-px block:
//   preamble: softmax over m from scores (LDS, 3 barriers, once per block)
//   m-loop  : wx[c,px] += p[m,px] * X[m,c,px] — pure per-thread FMA,
//             ZERO barriers/shuffles, 2-deep prefetch stays in flight.
//   epilogue: wx -> LDS slab, bf16 MFMA 16x16x32 conv vs WvB + bv (4 waves,
//             4 co-tiles each). Same math as the R3-verified epilogue.
// ---------------------------------------------------------------------------
__global__ __launch_bounds__(256) void wxconv_kernel(
    const float* __restrict__ X,      // [2,16,256,4096]
    const float* __restrict__ scores, // [2,16,4096]
    const unsigned short* __restrict__ WvB,  // [256,256] bf16
    const float* __restrict__ bv,     // [256]
    float* __restrict__ out)          // [2,256,4096]
{
    const int t   = threadIdx.x;
    const int blk = blockIdx.x;
    const int pb  = ((blk & 7) << 6) | (blk >> 3);   // XCD swizzle
    const int b   = pb >> 8;
    const int hw0 = (pb & 255) << 4;                 // 16 pixels

    __shared__ float pl[16][16];      // probs [m][px]
    __shared__ float invl[16];
    __shared__ float slab[256 * 20];  // wx[c][px], stride 20

    // ---- softmax preamble (once per block) ----
    {
        const int px_s = t & 15, m_s = t >> 4;
        const float e = __expf(scores[(b * 16 + m_s) * 4096 + hw0 + px_s]);
        pl[m_s][px_s] = e;
        __syncthreads();
        if (t < 16) {
            float s = 0.f;
#pragma unroll
            for (int m = 0; m < 16; ++m) s += pl[m][t];
            invl[t] = 1.0f / s;
        }
        __syncthreads();
        pl[m_s][px_s] *= invl[px_s];
        __syncthreads();
    }

    // ---- barrier-free weighted-sum loop ----
    const int p4 = t & 3;     // pixel quartet
    const int cg = t >> 2;    // 0..63 channel group (c = cg + 64k)
    const float4* X4 = (const float4*)X;
    const int base0 = (b * 16) * 262144 + (hw0 >> 2) + p4;  // float4 units

    float4 v[2][4];
    float4 wx[4];
#pragma unroll
    for (int k = 0; k < 4; ++k) wx[k] = make_float4(0.f, 0.f, 0.f, 0.f);

#pragma unroll
    for (int k = 0; k < 4; ++k)
        v[0][k] = X4[base0 + (cg + 64 * k) * 1024];
    float4 pm[2];
    pm[0] = *(const float4*)&pl[0][4 * p4];

#pragma unroll
    for (int m = 0; m < 16; ++m) {
        const int buf = m & 1, nxt = buf ^ 1;
        if (m < 15) {
#pragma unroll
            for (int k = 0; k < 4; ++k)
                v[nxt][k] = X4[base0 + (m + 1) * 262144 + (cg + 64 * k) * 1024];
            pm[nxt] = *(const float4*)&pl[m + 1][4 * p4];
        }
#pragma unroll
        for (int k = 0; k < 4; ++k) {
            wx[k].x = fmaf(pm[buf].x, v[buf][k].x, wx[k].x);
            wx[k].y = fmaf(pm[buf].y, v[buf][k].y, wx[k].y);
            wx[k].z = fmaf(pm[buf].z, v[buf][k].z, wx[k].z);
            wx[k].w = fmaf(pm[buf].w, v[buf][k].w, wx[k].w);
        }
    }

    // ---- park wx in LDS ----
#pragma unroll
    for (int k = 0; k < 4; ++k)
        *(float4*)&slab[(cg + 64 * k) * 20 + 4 * p4] = wx[k];
    __syncthreads();

    // ---- MFMA conv epilogue: out[co,px] = bv[co] + sum_o Wv[co][o] wx[o][px]
    const int w    = t >> 6;    // wave: co-tiles 4w..4w+3
    const int lane = t & 63;
    const int px   = lane & 15;
    const int quad = lane >> 4;

    f32x4 acc[4];
#pragma unroll
    for (int i = 0; i < 4; ++i) {
        const int tt = 4 * w + i;
#pragma unroll
        for (int r = 0; r < 4; ++r)
            acc[i][r] = bv[16 * tt + quad * 4 + r];
    }

#pragma unroll
    for (int ks = 0; ks < 8; ++ks) {   // K = 256 in steps of 32
        s16x8 bfr;
#pragma unroll
        for (int j = 0; j < 8; ++j)
            bfr[j] = (short)f2bf(slab[(ks * 32 + quad * 8 + j) * 20 + px]);
#pragma unroll
        for (int i = 0; i < 4; ++i) {
            const int tt = 4 * w + i;
            const s16x8 afr =
                *(const s16x8*)(WvB + (16 * tt + px) * 256 + ks * 32 + quad * 8);
            acc[i] = __builtin_amdgcn_mfma_f32_16x16x32_bf16(afr, bfr, acc[i],
                                                             0, 0, 0);
        }
    }

    const int obase = b * 1048576 + hw0;
#pragma unroll
    for (int i = 0; i < 4; ++i) {
        const int tt = 4 * w + i;
#pragma unroll
        for (int r = 0; r < 4; ++r) {
            const int co = 16 * tt + quad * 4 + r;
            out[obase + co * 4096 + px] = acc[i][r];
        }
    }
}

// ---------------------------------------------------------------------------
extern "C" void kernel_launch(void* const* d_in, const int* in_sizes, int n_in,
                              void* d_out, int out_size, void* d_ws, size_t ws_size,
                              hipStream_t stream) {
    const float* TO = (const float*)d_in[0];   // [2,1024]
    const float* X  = (const float*)d_in[1];   // [2,16,256,64,64]
    const float* Wq = (const float*)d_in[2];   // [256,1024]
    const float* bq = (const float*)d_in[3];   // [256]
    const float* Wk = (const float*)d_in[4];   // [256,256]
    // d_in[5] = bk: dropped (softmax-invariant)
    const float* Wv = (const float*)d_in[6];   // [256,256]
    const float* bv = (const float*)d_in[7];   // [256]
    float* out = (float*)d_out;
    float* ws  = (float*)d_ws;

    float*          qbuf   = ws;                            // 512 floats
    float*          qks    = ws + 512;                      // 512 floats
    unsigned short* WvB    = (unsigned short*)(ws + 1024);  // 65536 bf16 (32768 f)
    float*          scores = ws + 1024 + 32768;             // 131072 floats

    hipLaunchKernelGGL(prep1_kernel, dim3(32), dim3(256), 0, stream,
                       TO, Wq, bq, Wv, qbuf, WvB);
    hipLaunchKernelGGL(prep2_kernel, dim3(16), dim3(256), 0, stream,
                       qbuf, Wk, qks);
    hipLaunchKernelGGL(scores_kernel, dim3(512), dim3(256), 0, stream,
                       X, qks, scores);
    hipLaunchKernelGGL(wxconv_kernel, dim3(512), dim3(256), 0, stream,
                       X, scores, WvB, bv, out);
}

// Round 5
// 249.177 us; speedup vs baseline: 1.0072x; 1.0072x over previous
//
#include <hip/hip_runtime.h>

#define SCALE 0.0625f  // C^-0.5 = 1/16

typedef __attribute__((ext_vector_type(4))) float f32x4;
typedef __attribute__((ext_vector_type(8))) short s16x8;

__device__ __forceinline__ unsigned short f2bf(float x) {
    unsigned u = __float_as_uint(x);
    u = u + 0x7FFF + ((u >> 16) & 1);   // RNE; inputs finite
    return (unsigned short)(u >> 16);
}

// ---------------------------------------------------------------------------
// prep1: blocks 0..15  -> q[b,c] = TO[b] . Wq[c] + bq[c]
//        blocks 16..31 -> WvB = bf16(Wv)   (row-major [co][o])
// ---------------------------------------------------------------------------
__global__ __launch_bounds__(256) void prep1_kernel(
    const float* __restrict__ TO,    // [2,1024]
    const float* __restrict__ Wq,    // [256,1024]
    const float* __restrict__ bq,    // [256]
    const float* __restrict__ Wv,    // [256,256]
    float* __restrict__ qbuf,        // [2,256]
    unsigned short* __restrict__ WvB)// [256,256] bf16
{
    const int blk = blockIdx.x;
    const int t   = threadIdx.x;
    if (blk < 16) {
        const int b    = blk >> 3;
        const int rblk = blk & 7;
        const int wv = t >> 6, l = t & 63;
        const float4* Wq4 = (const float4*)Wq;
        const float4* TO4 = (const float4*)TO;
        for (int rr = 0; rr < 8; ++rr) {
            const int c = rblk * 32 + wv * 8 + rr;
            float acc = 0.f;
#pragma unroll
            for (int i = 0; i < 4; ++i) {
                float4 wq = Wq4[c * 256 + i * 64 + l];
                float4 tv = TO4[b * 256 + i * 64 + l];
                acc = fmaf(wq.x, tv.x, acc);
                acc = fmaf(wq.y, tv.y, acc);
                acc = fmaf(wq.z, tv.z, acc);
                acc = fmaf(wq.w, tv.w, acc);
            }
#pragma unroll
            for (int mask = 1; mask < 64; mask <<= 1)
                acc += __shfl_xor(acc, mask, 64);
            if (l == 0) qbuf[b * 256 + c] = acc + bq[c];
        }
    } else {
        const int idx = blk - 16;   // 0..15, 4096 elements each
#pragma unroll
        for (int i = 0; i < 4; ++i) {
            const int e = idx * 4096 + i * 1024 + t * 4;
            const float4 f = ((const float4*)Wv)[e >> 2];
            ushort4 o;
            o.x = f2bf(f.x); o.y = f2bf(f.y);
            o.z = f2bf(f.z); o.w = f2bf(f.w);
            *(ushort4*)(WvB + e) = o;
        }
    }
}

// ---------------------------------------------------------------------------
// prep2: 16 blocks: qks[b,cp] = SCALE * sum_c q[c] Wk[c][cp]
// (q.bk term dropped: softmax-invariant)
// ---------------------------------------------------------------------------
__global__ __launch_bounds__(256) void prep2_kernel(
    const float* __restrict__ qbuf,  // [2,256]
    const float* __restrict__ Wk,    // [256,256]
    float* __restrict__ qks)         // [2,256] (pre-scaled)
{
    const int blk = blockIdx.x;
    const int t   = threadIdx.x;
    const int b = blk >> 3, j = blk & 7;
    const int col = t & 31, chunk = t >> 5;
    const int cp = j * 32 + col;
    float partial = 0.f;
#pragma unroll 8
    for (int cc = 0; cc < 32; ++cc) {
        const int c = chunk * 32 + cc;
        partial = fmaf(qbuf[b * 256 + c], Wk[c * 256 + cp], partial);
    }
    __shared__ float r2[8][32];
    r2[chunk][col] = partial;
    __syncthreads();
    if (t < 32) {
        float s = 0.f;
#pragma unroll
        for (int k = 0; k < 8; ++k) s += r2[k][t];
        qks[b * 256 + j * 32 + t] = SCALE * s;
    }
}

// ---------------------------------------------------------------------------
// fused main: 256 blocks x 512 thr. Block = (b, 32-pixel tile) -> every load
// instruction covers full 128B lines.
//  Phase A (scores): thread = (px = t&31, m = t>>5). 256-ch dot with 8
//    independent accumulators -> 32 coalesced loads in flight/lane, no
//    barriers. exp() -> LDS pl[16][32]; softmax over m (3 barriers, once).
//  Phase B (wx): thread = (cg = t>>3, p4 = t&7). Triple-buffered prefetch,
//    ZERO barriers in the m-loop; X re-read is L3-resident from phase A.
//  Epilogue: wx -> LDS slab (stride 36), bf16 MFMA 16x16x32 conv vs WvB+bv;
//    8 waves = 2 px-halves x 4 co-tile groups. (R3/R4-verified math.)
// ---------------------------------------------------------------------------
__global__ __launch_bounds__(512, 1) void fused_kernel(
    const float* __restrict__ X,      // [2,16,256,4096]
    const float* __restrict__ qks,    // [2,256]
    const unsigned short* __restrict__ WvB,  // [256,256] bf16
    const float* __restrict__ bv,     // [256]
    float* __restrict__ out)          // [2,256,4096]
{
    const int t   = threadIdx.x;
    const int blk = blockIdx.x;       // 0..255
    const int b   = blk >> 7;
    const int hw0 = (blk & 127) << 5; // 32 pixels

    __shared__ float pl[16][32];      // probs [m][px]
    __shared__ float invl[32];
    __shared__ float slab[256 * 36];  // wx[c][px], stride 36

    // ---- phase A: scores + softmax ----
    {
        const int px = t & 31, ms = t >> 5;
        const float* __restrict__ Xr = X + ((b * 16 + ms) * 256) * 4096 + hw0 + px;
        const float* __restrict__ qr = qks + b * 256;
        float a0 = 0.f, a1 = 0.f, a2 = 0.f, a3 = 0.f;
        float a4 = 0.f, a5 = 0.f, a6 = 0.f, a7 = 0.f;
#pragma unroll 4
        for (int c = 0; c < 256; c += 8) {
            a0 = fmaf(qr[c + 0], Xr[(c + 0) * 4096], a0);
            a1 = fmaf(qr[c + 1], Xr[(c + 1) * 4096], a1);
            a2 = fmaf(qr[c + 2], Xr[(c + 2) * 4096], a2);
            a3 = fmaf(qr[c + 3], Xr[(c + 3) * 4096], a3);
            a4 = fmaf(qr[c + 4], Xr[(c + 4) * 4096], a4);
            a5 = fmaf(qr[c + 5], Xr[(c + 5) * 4096], a5);
            a6 = fmaf(qr[c + 6], Xr[(c + 6) * 4096], a6);
            a7 = fmaf(qr[c + 7], Xr[(c + 7) * 4096], a7);
        }
        const float s = ((a0 + a1) + (a2 + a3)) + ((a4 + a5) + (a6 + a7));
        pl[ms][px] = __expf(s);
        __syncthreads();
        if (t < 32) {
            float sm = 0.f;
#pragma unroll
            for (int m = 0; m < 16; ++m) sm += pl[m][t];
            invl[t] = 1.0f / sm;
        }
        __syncthreads();
        pl[ms][px] *= invl[px];
        __syncthreads();
    }

    // ---- phase B: barrier-free weighted sum (X now L3-resident) ----
    const int p4 = t & 7;     // pixel quartet: px 4*p4..4*p4+3
    const int cg = t >> 3;    // 0..63 (c = cg + 64k)
    const float4* X4 = (const float4*)X;
    const int base0 = (b * 16) * 262144 + (hw0 >> 2) + p4;  // float4 units

    float4 v[3][4];
    float4 wx[4];
#pragma unroll
    for (int k = 0; k < 4; ++k) wx[k] = make_float4(0.f, 0.f, 0.f, 0.f);

#pragma unroll
    for (int k = 0; k < 4; ++k)
        v[0][k] = X4[base0 + (cg + 64 * k) * 1024];
#pragma unroll
    for (int k = 0; k < 4; ++k)
        v[1][k] = X4[base0 + 262144 + (cg + 64 * k) * 1024];

#pragma unroll
    for (int m = 0; m < 16; ++m) {
        const int cur = m % 3;
        const int nxt = (m + 2) % 3;
        if (m < 14) {
#pragma unroll
            for (int k = 0; k < 4; ++k)
                v[nxt][k] = X4[base0 + (m + 2) * 262144 + (cg + 64 * k) * 1024];
        }
        const float4 pm = *(const float4*)&pl[m][4 * p4];
#pragma unroll
        for (int k = 0; k < 4; ++k) {
            wx[k].x = fmaf(pm.x, v[cur][k].x, wx[k].x);
            wx[k].y = fmaf(pm.y, v[cur][k].y, wx[k].y);
            wx[k].z = fmaf(pm.z, v[cur][k].z, wx[k].z);
            wx[k].w = fmaf(pm.w, v[cur][k].w, wx[k].w);
        }
    }

    // ---- park wx in LDS ----
#pragma unroll
    for (int k = 0; k < 4; ++k)
        *(float4*)&slab[(cg + 64 * k) * 36 + 4 * p4] = wx[k];
    __syncthreads();

    // ---- MFMA conv epilogue: out[co,px] = bv[co] + sum_o Wv[co][o] wx[o][px]
    const int w    = t >> 6;          // wave 0..7
    const int ph   = w & 1;           // px half: px 16*ph + (lane&15)
    const int cot  = w >> 1;          // co-tile group: tt = 4*cot + i
    const int lane = t & 63;
    const int pxl  = lane & 15;
    const int quad = lane >> 4;
    const int px   = 16 * ph + pxl;

    f32x4 acc[4];
#pragma unroll
    for (int i = 0; i < 4; ++i) {
        const int tt = 4 * cot + i;
#pragma unroll
        for (int r = 0; r < 4; ++r)
            acc[i][r] = bv[16 * tt + quad * 4 + r];
    }

#pragma unroll
    for (int ks = 0; ks < 8; ++ks) {   // K = 256 in steps of 32
        s16x8 bfr;
#pragma unroll
        for (int j = 0; j < 8; ++j)
            bfr[j] = (short)f2bf(slab[(ks * 32 + quad * 8 + j) * 36 + px]);
#pragma unroll
        for (int i = 0; i < 4; ++i) {
            const int tt = 4 * cot + i;
            const s16x8 afr =
                *(const s16x8*)(WvB + (16 * tt + pxl) * 256 + ks * 32 + quad * 8);
            acc[i] = __builtin_amdgcn_mfma_f32_16x16x32_bf16(afr, bfr, acc[i],
                                                             0, 0, 0);
        }
    }

    const int obase = b * 1048576 + hw0;
#pragma unroll
    for (int i = 0; i < 4; ++i) {
        const int tt = 4 * cot + i;
#pragma unroll
        for (int r = 0; r < 4; ++r) {
            const int co = 16 * tt + quad * 4 + r;
            out[obase + co * 4096 + px] = acc[i][r];
        }
    }
}

// ---------------------------------------------------------------------------
extern "C" void kernel_launch(void* const* d_in, const int* in_sizes, int n_in,
                              void* d_out, int out_size, void* d_ws, size_t ws_size,
                              hipStream_t stream) {
    const float* TO = (const float*)d_in[0];   // [2,1024]
    const float* X  = (const float*)d_in[1];   // [2,16,256,64,64]
    const float* Wq = (const float*)d_in[2];   // [256,1024]
    const float* bq = (const float*)d_in[3];   // [256]
    const float* Wk = (const float*)d_in[4];   // [256,256]
    // d_in[5] = bk: dropped (softmax-invariant)
    const float* Wv = (const float*)d_in[6];   // [256,256]
    const float* bv = (const float*)d_in[7];   // [256]
    float* out = (float*)d_out;
    float* ws  = (float*)d_ws;

    float*          qbuf = ws;                              // 512 floats
    float*          qks  = ws + 512;                        // 512 floats
    unsigned short* WvB  = (unsigned short*)(ws + 1024);    // 65536 bf16

    hipLaunchKernelGGL(prep1_kernel, dim3(32), dim3(256), 0, stream,
                       TO, Wq, bq, Wv, qbuf, WvB);
    hipLaunchKernelGGL(prep2_kernel, dim3(16), dim3(256), 0, stream,
                       qbuf, Wk, qks);
    hipLaunchKernelGGL(fused_kernel, dim3(256), dim3(512), 0, stream,
                       X, qks, WvB, bv, out);
}